// Round 4
// baseline (332.973 us; speedup 1.0000x reference)
//
#include <hip/hip_runtime.h>

// Problem constants
#define N 8
#define C 64
#define H 256
#define W 256
#define G 8
#define CG 8            // C/G
#define KK 9            // 3x3
#define HW (H*W)        // 65536

// native clang vector type for nontemporal builtins (HIP_vector_type is invalid there)
typedef float nfloat4 __attribute__((ext_vector_type(4)));

// ---------------------------------------------------------------------------
// Kernel 1: global average pool per (n,c).  One block per (n,c), 1024 threads
// (16 waves -> 2 blocks/CU = 32 waves/CU, full occupancy), float4 loads,
// wave-shuffle reduce.
// ---------------------------------------------------------------------------
__global__ __launch_bounds__(1024) void gap_kernel(const float* __restrict__ x,
                                                   float* __restrict__ gap) {
    const int nc = blockIdx.x;                     // 0..511
    const float4* x4 = (const float4*)(x + (size_t)nc * HW);
    float s = 0.f;
    // 16384 float4 / 1024 threads -> 16 iters each
    #pragma unroll 4
    for (int i = threadIdx.x; i < HW / 4; i += 1024) {
        float4 v = x4[i];
        s += (v.x + v.y) + (v.z + v.w);
    }
    // wave (64-lane) shuffle reduce
    #pragma unroll
    for (int off = 32; off > 0; off >>= 1)
        s += __shfl_down(s, off, 64);
    __shared__ float red[16];
    const int wave = threadIdx.x >> 6;
    const int lane = threadIdx.x & 63;
    if (lane == 0) red[wave] = s;
    __syncthreads();
    if (threadIdx.x == 0) {
        float t = 0.f;
        #pragma unroll
        for (int wv = 0; wv < 16; ++wv) t += red[wv];
        gap[nc] = t * (1.0f / (float)HW);
    }
}

// ---------------------------------------------------------------------------
// Kernel 2 (fused): per-block recompute of the 9 dynamic filter taps for its
// (n,g), then out[n,c,h,w] = x + sum_{i,j} xp[...]*f[ij], reflect padding.
// Block = 256 threads = 4 rows x 64 lanes; each thread emits one float4.
// Grid = N*C*(H/4) = 32768 blocks.
// ---------------------------------------------------------------------------
__global__ __launch_bounds__(256) void dynconv_kernel(const float* __restrict__ x,
                                                      const float* __restrict__ gap,
                                                      const float* __restrict__ conv_w,
                                                      float* __restrict__ out) {
    const int bid = blockIdx.x;
    const int rowblk = bid & (H / 4 - 1);          // 0..63
    const int nc = bid >> 6;                       // n*C + c
    const int n = nc >> 6;
    const int c = nc & (C - 1);
    const int g = c >> 3;                          // c / CG

    // --- wave 0 computes the 9 filter taps: f[o] = tanh(dot(gap[n,:], W[g*9+o,:]))
    __shared__ float fsh[KK];
    const int tid = threadIdx.x;
    if (tid < 64) {
        const float gv = gap[n * C + tid];         // lane = channel
        #pragma unroll
        for (int o = 0; o < KK; ++o) {
            float p = gv * conv_w[(g * KK + o) * C + tid];
            #pragma unroll
            for (int off = 32; off > 0; off >>= 1)
                p += __shfl_down(p, off, 64);
            if (tid == 0) fsh[o] = tanhf(p);
        }
    }
    __syncthreads();
    const float f00 = fsh[0], f01 = fsh[1], f02 = fsh[2];
    const float f10 = fsh[3], f11 = fsh[4], f12 = fsh[5];
    const float f20 = fsh[6], f21 = fsh[7], f22 = fsh[8];

    const int lrow = tid >> 6;                     // 0..3
    const int wq = (tid & 63) * 4;                 // base column of the float4
    const int hrow = rowblk * 4 + lrow;

    const float* xc = x + (size_t)nc * HW;
    // reflect rows (exclude-edge): -1 -> 1, H -> H-2
    int hm = hrow - 1; if (hm < 0) hm = 1;
    int hp = hrow + 1; if (hp >= H) hp = H - 2;

    const float* rm = xc + (size_t)hm * W;
    const float* rc = xc + (size_t)hrow * W;
    const float* rp = xc + (size_t)hp * W;

    // Load 6-wide strips [wq-1 .. wq+4] for each of the 3 rows (reflect cols)
    float vm[6], vc[6], vp[6];
    {
        float4 a = *(const float4*)(rm + wq);
        vm[1] = a.x; vm[2] = a.y; vm[3] = a.z; vm[4] = a.w;
        vm[0] = (wq == 0) ? rm[1] : rm[wq - 1];
        vm[5] = (wq == W - 4) ? rm[W - 2] : rm[wq + 4];
    }
    {
        float4 a = *(const float4*)(rc + wq);
        vc[1] = a.x; vc[2] = a.y; vc[3] = a.z; vc[4] = a.w;
        vc[0] = (wq == 0) ? rc[1] : rc[wq - 1];
        vc[5] = (wq == W - 4) ? rc[W - 2] : rc[wq + 4];
    }
    {
        float4 a = *(const float4*)(rp + wq);
        vp[1] = a.x; vp[2] = a.y; vp[3] = a.z; vp[4] = a.w;
        vp[0] = (wq == 0) ? rp[1] : rp[wq - 1];
        vp[5] = (wq == W - 4) ? rp[W - 2] : rp[wq + 4];
    }

    nfloat4 r;
    #pragma unroll
    for (int k = 0; k < 4; ++k) {
        float acc = vc[k + 1];                     // residual x
        acc += f00 * vm[k] + f01 * vm[k + 1] + f02 * vm[k + 2];
        acc += f10 * vc[k] + f11 * vc[k + 1] + f12 * vc[k + 2];
        acc += f20 * vp[k] + f21 * vp[k + 1] + f22 * vp[k + 2];
        r[k] = acc;
    }

    // out is never re-read: non-temporal store keeps x resident in L3
    __builtin_nontemporal_store(r, (nfloat4*)(out + (size_t)nc * HW + (size_t)hrow * W + wq));
}

// ---------------------------------------------------------------------------
extern "C" void kernel_launch(void* const* d_in, const int* in_sizes, int n_in,
                              void* d_out, int out_size, void* d_ws, size_t ws_size,
                              hipStream_t stream) {
    const float* x      = (const float*)d_in[0];
    const float* conv_w = (const float*)d_in[1];
    float* out = (float*)d_out;

    float* gap = (float*)d_ws;                     // 512 floats

    gap_kernel<<<N * C, 1024, 0, stream>>>(x, gap);
    dynconv_kernel<<<N * C * (H / 4), 256, 0, stream>>>(x, gap, conv_w, out);
}

// Round 5
// 253.670 us; speedup vs baseline: 1.3126x; 1.3126x over previous
//
#include <hip/hip_runtime.h>

// Problem constants
#define N 8
#define C 64
#define H 256
#define W 256
#define G 8
#define CG 8            // C/G
#define KK 9            // 3x3
#define HW (H*W)        // 65536

// native clang vector type for nontemporal builtins (HIP_vector_type is invalid there)
typedef float nfloat4 __attribute__((ext_vector_type(4)));

// ---------------------------------------------------------------------------
// Kernel 1: global average pool per (n,c).  One block per (n,c), 1024 threads,
// float4 loads, wave-shuffle reduce.  512 blocks -> 2 blocks/CU, 32 waves/CU.
// ---------------------------------------------------------------------------
__global__ __launch_bounds__(1024) void gap_kernel(const float* __restrict__ x,
                                                   float* __restrict__ gap) {
    const int nc = blockIdx.x;                     // 0..511
    const float4* x4 = (const float4*)(x + (size_t)nc * HW);
    float s = 0.f;
    // 16384 float4 / 1024 threads -> 16 iters each
    #pragma unroll 8
    for (int i = threadIdx.x; i < HW / 4; i += 1024) {
        float4 v = x4[i];
        s += (v.x + v.y) + (v.z + v.w);
    }
    #pragma unroll
    for (int off = 32; off > 0; off >>= 1)
        s += __shfl_down(s, off, 64);
    __shared__ float red[16];
    const int wave = threadIdx.x >> 6;
    const int lane = threadIdx.x & 63;
    if (lane == 0) red[wave] = s;
    __syncthreads();
    if (threadIdx.x == 0) {
        float t = 0.f;
        #pragma unroll
        for (int wv = 0; wv < 16; ++wv) t += red[wv];
        gap[nc] = t * (1.0f / (float)HW);
    }
}

// ---------------------------------------------------------------------------
// Kernel 2: filt[n, o] = tanh( dot(gap[n,:], conv_w[o,:]) ), 576 outputs.
// ---------------------------------------------------------------------------
__global__ __launch_bounds__(256) void filt_kernel(const float* __restrict__ gap,
                                                   const float* __restrict__ conv_w,
                                                   float* __restrict__ filt) {
    const int idx = blockIdx.x * 256 + threadIdx.x;
    if (idx >= N * G * KK) return;
    const int n = idx / (G * KK);
    const int o = idx - n * (G * KK);
    const float* gp = gap + n * C;
    const float* wp = conv_w + o * C;
    float s = 0.f;
    #pragma unroll
    for (int c = 0; c < C; ++c) s += gp[c] * wp[c];
    filt[idx] = tanhf(s);
}

// ---------------------------------------------------------------------------
// Kernel 3: strip-mined dynamic 3x3 conv + residual, reflect padding.
// Block = 256 threads = 4 waves; wave = 64 lanes = one full row (64 float4).
// Each wave processes 16 consecutive rows with a 3-row rolling register
// window; left/right halos via __shfl (reflect at lanes 0/63).
// Grid = N*C*(H/64) = 2048 blocks = exactly 8 blocks/CU.
// ---------------------------------------------------------------------------
__device__ __forceinline__ void load_row(const float* __restrict__ xc, int rr,
                                         int lane, float4& v, float& l, float& r) {
    rr = (rr < 0) ? 1 : (rr >= H ? H - 2 : rr);    // reflect (exclude-edge)
    v = *(const float4*)(xc + (size_t)rr * W + lane * 4);
    const float lu = __shfl_up(v.w, 1, 64);
    const float rd = __shfl_down(v.x, 1, 64);
    l = (lane == 0) ? v.y : lu;                    // col -1 -> col 1
    r = (lane == 63) ? v.z : rd;                   // col W -> col W-2
}

__global__ __launch_bounds__(256) void dynconv_kernel(const float* __restrict__ x,
                                                      const float* __restrict__ filt,
                                                      float* __restrict__ out) {
    const int bid = blockIdx.x;                    // 0..2047
    const int rb = bid & 3;                        // which 64-row chunk
    const int nc = bid >> 2;                       // n*C + c
    const int n = nc >> 6;
    const int c = nc & (C - 1);
    const int g = c >> 3;

    // block-uniform filter -> scalar loads, no prologue serialization
    const float* f = filt + ((size_t)n * G + g) * KK;
    const float f00 = f[0], f01 = f[1], f02 = f[2];
    const float f10 = f[3], f11 = f[4], f12 = f[5];
    const float f20 = f[6], f21 = f[7], f22 = f[8];

    const int wave = threadIdx.x >> 6;
    const int lane = threadIdx.x & 63;
    const int base = rb * 64 + wave * 16;          // first row of this wave's strip

    const float* xc = x + (size_t)nc * HW;
    float* oc = out + (size_t)nc * HW;

    float4 a4, b4, c4;
    float al, ar, bl, br, cl, cr;
    load_row(xc, base - 1, lane, a4, al, ar);
    load_row(xc, base,     lane, b4, bl, br);

    #pragma unroll 4
    for (int i = 0; i < 16; ++i) {
        load_row(xc, base + i + 1, lane, c4, cl, cr);

        const float am[6] = {al, a4.x, a4.y, a4.z, a4.w, ar};
        const float bm[6] = {bl, b4.x, b4.y, b4.z, b4.w, br};
        const float cm[6] = {cl, c4.x, c4.y, c4.z, c4.w, cr};

        nfloat4 o;
        #pragma unroll
        for (int k = 0; k < 4; ++k) {
            float acc = bm[k + 1];                 // residual
            acc += f00 * am[k] + f01 * am[k + 1] + f02 * am[k + 2];
            acc += f10 * bm[k] + f11 * bm[k + 1] + f12 * bm[k + 2];
            acc += f20 * cm[k] + f21 * cm[k + 1] + f22 * cm[k + 2];
            o[k] = acc;
        }
        __builtin_nontemporal_store(o, (nfloat4*)(oc + (size_t)(base + i) * W + lane * 4));

        a4 = b4; al = bl; ar = br;
        b4 = c4; bl = cl; br = cr;
    }
}

// ---------------------------------------------------------------------------
extern "C" void kernel_launch(void* const* d_in, const int* in_sizes, int n_in,
                              void* d_out, int out_size, void* d_ws, size_t ws_size,
                              hipStream_t stream) {
    const float* x      = (const float*)d_in[0];
    const float* conv_w = (const float*)d_in[1];
    float* out = (float*)d_out;

    float* gap  = (float*)d_ws;                    // 512 floats
    float* filt = (float*)d_ws + 512;              // 576 floats

    gap_kernel<<<N * C, 1024, 0, stream>>>(x, gap);
    filt_kernel<<<(N * G * KK + 255) / 256, 256, 0, stream>>>(gap, conv_w, filt);
    dynconv_kernel<<<N * C * (H / 64), 256, 0, stream>>>(x, filt, out);
}